// Round 2
// baseline (329.531 us; speedup 1.0000x reference)
//
#include <hip/hip_runtime.h>

// EKF_v2: B=16384, N=128, DX=5, DZ=2.
// Block = 256 threads = 4 waves; each WAVE owns one batch (64 lanes, 2
// particles/lane: p = lane and lane+64). All reductions are in-wave
// butterflies; single __syncthreads after LDS staging.

#define BPB 4

__global__ __launch_bounds__(256, 6) void ekf_fused(
    const float* __restrict__ state_old,  // (B,128,5)
    const float* __restrict__ y_obs,      // (B,128,2)
    const float* __restrict__ encoding,   // (B,128)
    const float* __restrict__ pw1,        // (2,16)
    const float* __restrict__ pb1,        // (16)
    const float* __restrict__ pw2,        // (16,32)
    const float* __restrict__ pb2,        // (32)
    const float* __restrict__ pw3,        // (32,2)
    const float* __restrict__ pb3,        // (2)
    const float* __restrict__ nw1,        // (128,32)
    const float* __restrict__ nb1,        // (32)
    const float* __restrict__ nw2,        // (32,2)
    const float* __restrict__ nb2,        // (2)
    const float* __restrict__ lob,        // (2)
    const float* __restrict__ fob,        // (2)
    float* __restrict__ out)              // (B,128,5)
{
    __shared__ __align__(16) float s_state[BPB * 640];
    __shared__ __align__(16) float s_enc[BPB * 128];
    __shared__ __align__(16) float s_pw2t[512]; // [j][k] = pw2[k][j]
    __shared__ float s_pw1[32];
    __shared__ float s_pb1[16];
    __shared__ float s_pb2[32];
    __shared__ float s_pw3[64];
    __shared__ float s_nb1[32];
    __shared__ float s_nw2[64];
    __shared__ float s_pb3[2];
    __shared__ float s_nb2[2];
    __shared__ float s_bias[4]; // lob0, lob1, fob0, fob1

    const int t = threadIdx.x;
    const int base = blockIdx.x * BPB;

    // ---- stage (coalesced float4) ----
    {
        const float4* src = (const float4*)(state_old + (size_t)base * 640);
        float4* dst = (float4*)s_state;
        #pragma unroll
        for (int i = t; i < BPB * 160; i += 256) dst[i] = src[i];
        const float4* se = (const float4*)(encoding + (size_t)base * 128);
        float4* de = (float4*)s_enc;
        if (t < BPB * 32) de[t] = se[t];
    }
    if (t < 32) { s_pw1[t] = pw1[t]; s_pb2[t] = pb2[t]; s_nb1[t] = nb1[t]; }
    if (t < 16) s_pb1[t] = pb1[t];
    if (t < 64) { s_pw3[t] = pw3[t]; s_nw2[t] = nw2[t]; }
    if (t < 2)  { s_pb3[t] = pb3[t]; s_nb2[t] = nb2[t]; s_bias[t] = lob[t]; s_bias[2 + t] = fob[t]; }
    #pragma unroll
    for (int i = t; i < 512; i += 256) { int j = i >> 4, k = i & 15; s_pw2t[i] = pw2[k * 32 + j]; }
    __syncthreads();

    const int w = t >> 6;   // wave index = batch within block
    const int l = t & 63;   // lane
    const size_t b = (size_t)base + w;

    // ---- noise MLP partial sums (issue L2 loads early; 4 indep chains) ----
    const int j = l & 31;
    const int kh = (l & 32) << 1; // 0 or 64: lane-half splits k
    float na0 = 0.f, na1 = 0.f, na2 = 0.f, na3 = 0.f;
    {
        const float* eg = s_enc + w * 128 + kh;
        const float* wp = nw1 + (size_t)kh * 32 + j;
        #pragma unroll 8
        for (int k = 0; k < 64; k += 4) {
            na0 = fmaf(eg[k + 0], wp[(k + 0) * 32], na0);
            na1 = fmaf(eg[k + 1], wp[(k + 1) * 32], na1);
            na2 = fmaf(eg[k + 2], wp[(k + 2) * 32], na2);
            na3 = fmaf(eg[k + 3], wp[(k + 3) * 32], na3);
        }
    }

    // ---- process model: 2 particles/lane (p = l, l+64) ----
    float xp[2][5];
    float h1[2][16];
    #pragma unroll
    for (int m = 0; m < 2; ++m) {
        const float* s = s_state + w * 640 + (l + 64 * m) * 5;
        float s0 = s[0], s1 = s[1], s2 = s[2], v = s[3], td = s[4];
        float theta = s2 + td;
        float sn, cs;
        __sincosf(theta, &sn, &cs);
        xp[m][0] = fmaf(v, sn, s0);
        xp[m][1] = fmaf(v, cs, s1);
        xp[m][2] = theta;
        xp[m][3] = v;
        xp[m][4] = td;
        #pragma unroll
        for (int q = 0; q < 16; ++q)
            h1[m][q] = fmaxf(0.0f, fmaf(v, s_pw1[q], fmaf(td, s_pw1[16 + q], s_pb1[q])));
    }

    // ---- layers 2+3 fused ----
    float o3[2] = {0.f, 0.f}, o4[2] = {0.f, 0.f};
    const float4* w2v = (const float4*)s_pw2t;
    #pragma unroll
    for (int jj = 0; jj < 32; ++jj) {
        float acc[2];
        acc[0] = s_pb2[jj]; acc[1] = s_pb2[jj];
        #pragma unroll
        for (int q = 0; q < 4; ++q) {
            float4 wv = w2v[jj * 4 + q];
            #pragma unroll
            for (int m = 0; m < 2; ++m) {
                acc[m] = fmaf(h1[m][4 * q + 0], wv.x, acc[m]);
                acc[m] = fmaf(h1[m][4 * q + 1], wv.y, acc[m]);
                acc[m] = fmaf(h1[m][4 * q + 2], wv.z, acc[m]);
                acc[m] = fmaf(h1[m][4 * q + 3], wv.w, acc[m]);
            }
        }
        float w30 = s_pw3[2 * jj], w31 = s_pw3[2 * jj + 1];
        #pragma unroll
        for (int m = 0; m < 2; ++m) {
            float r = fmaxf(acc[m], 0.0f);
            o3[m] = fmaf(r, w30, o3[m]);
            o4[m] = fmaf(r, w31, o4[m]);
        }
    }
    #pragma unroll
    for (int m = 0; m < 2; ++m) {
        xp[m][3] += o3[m] + s_pb3[0];
        xp[m][4] += o4[m] + s_pb3[1];
    }

    // ---- raw-moment reductions: 15 independent butterfly chains ----
    // red[0..4]  = sum_p xp_i
    // red[5+2i+z] = sum_p xp_i * xp_{3+z}
    float red[15];
    #pragma unroll
    for (int i = 0; i < 5; ++i) red[i] = xp[0][i] + xp[1][i];
    #pragma unroll
    for (int i = 0; i < 5; ++i) {
        #pragma unroll
        for (int z = 0; z < 2; ++z)
            red[5 + 2 * i + z] = xp[0][i] * xp[0][3 + z] + xp[1][i] * xp[1][3 + z];
    }
    #pragma unroll
    for (int off = 1; off < 64; off <<= 1) {
        #pragma unroll
        for (int r = 0; r < 15; ++r)
            red[r] += __shfl_xor(red[r], off, 64);
    }

    // ---- finish noise MLP (combine k-halves, butterfly over 32 j's) ----
    float diag0, diag1;
    {
        float acc = (na0 + na1) + (na2 + na3);
        acc += __shfl_xor(acc, 32, 64); // combine k-halves
        acc += s_nb1[j];
        float h = fmaxf(acc, 0.0f);
        float d0 = h * s_nw2[2 * j + 0];
        float d1 = h * s_nw2[2 * j + 1];
        #pragma unroll
        for (int off = 1; off < 32; off <<= 1) {
            d0 += __shfl_xor(d0, off, 64);
            d1 += __shfl_xor(d1, off, 64);
        }
        float e0 = d0 + s_nb2[0] + s_bias[0];
        float e1 = d1 + s_nb2[1] + s_bias[1];
        diag0 = fmaf(e0, e0, s_bias[2]);
        diag1 = fmaf(e1, e1, s_bias[3]);
    }

    // ---- covariances + analytic 2x2 solve ----
    const float inv  = 1.0f / 127.0f;
    const float minv = inv * 0.0078125f; // 1/(127*128)
    float S[5][2];
    #pragma unroll
    for (int i = 0; i < 5; ++i) {
        #pragma unroll
        for (int z = 0; z < 2; ++z)
            S[i][z] = red[5 + 2 * i + z] * inv - red[i] * red[3 + z] * minv;
    }
    float p00 = S[3][0] + diag0;
    float p01 = S[3][1];
    float p10 = S[4][0];
    float p11 = S[4][1] + diag1;
    float rdet = 1.0f / (p00 * p11 - p01 * p10);
    float Kt0[5], Kt1[5];
    #pragma unroll
    for (int i = 0; i < 5; ++i) {
        Kt0[i] = (p11 * S[i][0] - p01 * S[i][1]) * rdet;
        Kt1[i] = (p00 * S[i][1] - p10 * S[i][0]) * rdet;
    }

    // ---- Kalman update, direct global stores (L2 merges lines) ----
    #pragma unroll
    for (int m = 0; m < 2; ++m) {
        const int p = l + 64 * m;
        const float2 yy = *(const float2*)(y_obs + (b * 128 + p) * 2);
        float i0 = yy.x - xp[m][3];
        float i1 = yy.y - xp[m][4];
        float* o = out + (b * 128 + p) * 5;
        #pragma unroll
        for (int i = 0; i < 5; ++i)
            o[i] = xp[m][i] + i0 * Kt0[i] + i1 * Kt1[i];
    }
}

extern "C" void kernel_launch(void* const* d_in, const int* in_sizes, int n_in,
                              void* d_out, int out_size, void* d_ws, size_t ws_size,
                              hipStream_t stream) {
    const float* state_old = (const float*)d_in[0];
    const float* y_obs     = (const float*)d_in[1];
    const float* encoding  = (const float*)d_in[2];
    const float* pw1 = (const float*)d_in[3];
    const float* pb1 = (const float*)d_in[4];
    const float* pw2 = (const float*)d_in[5];
    const float* pb2 = (const float*)d_in[6];
    const float* pw3 = (const float*)d_in[7];
    const float* pb3 = (const float*)d_in[8];
    const float* nw1 = (const float*)d_in[9];
    const float* nb1 = (const float*)d_in[10];
    const float* nw2 = (const float*)d_in[11];
    const float* nb2 = (const float*)d_in[12];
    const float* lob = (const float*)d_in[13];
    const float* fob = (const float*)d_in[14];
    float* out = (float*)d_out;

    const int B = 16384;
    dim3 grid(B / BPB);
    dim3 block(256);
    hipLaunchKernelGGL(ekf_fused, grid, block, 0, stream,
                       state_old, y_obs, encoding,
                       pw1, pb1, pw2, pb2, pw3, pb3,
                       nw1, nb1, nw2, nb2, lob, fob, out);
}